// Round 1
// baseline (4296.317 us; speedup 1.0000x reference)
//
#include <hip/hip_runtime.h>

#define N_NODES 100000
#define N_EDGES 1600000
#define IN_DIM 64
#define HID_DIM 128
#define EMB_DIM 64

// ---------------- edge dtype handling ----------------
// Reference declares int64 edge_index, but JAX without x64 silently gives
// int32. Detect on device: for little-endian int64 with values in [0,1e5),
// every odd dword is 0. For int32 random values, impossible for 64 in a row.
__global__ void k_detect_dtype(const unsigned int* __restrict__ ebuf, int* __restrict__ flag) {
    if (blockIdx.x == 0 && threadIdx.x == 0) {
        int is64 = 1;
        for (int i = 0; i < 64; ++i)
            if (ebuf[2 * i + 1] != 0u) { is64 = 0; break; }
        *flag = is64;
    }
}

__global__ void k_convert_edges(const void* __restrict__ ebuf, const int* __restrict__ flag,
                                int* __restrict__ edges32) {
    int i = blockIdx.x * blockDim.x + threadIdx.x;
    if (i < 2 * N_EDGES) {
        int v;
        if (*flag) v = (int)((const long long*)ebuf)[i];
        else       v = ((const int*)ebuf)[i];
        edges32[i] = v;
    }
}

// ---------------- degree / normalization ----------------
__global__ void k_deg(const int* __restrict__ col, int* __restrict__ deg) {
    int e = blockIdx.x * blockDim.x + threadIdx.x;
    if (e < N_EDGES) atomicAdd(&deg[col[e]], 1);
}

__global__ void k_dinv(const int* __restrict__ deg, float* __restrict__ dinv) {
    int i = blockIdx.x * blockDim.x + threadIdx.x;
    if (i < N_NODES) dinv[i] = rsqrtf((float)(deg[i] + 1)); // +1 self loop
}

// ---------------- GEMM1: h1 = x @ W1  (100000x64 @ 64x128) ----------------
__global__ __launch_bounds__(256) void k_gemm1(const float* __restrict__ x,
                                               const float* __restrict__ W1,
                                               float* __restrict__ h1) {
    __shared__ float sW[IN_DIM * HID_DIM]; // 32 KB
    __shared__ float sX[8 * IN_DIM];       // 2 KB
    int t = threadIdx.x;
    long row0 = (long)blockIdx.x * 8;
    for (int i = t; i < IN_DIM * HID_DIM; i += 256) sW[i] = W1[i];
    for (int i = t; i < 8 * IN_DIM; i += 256) sX[i] = x[row0 * IN_DIM + i];
    __syncthreads();
    int c  = t & 127;
    int rh = t >> 7; // 0..1, owns rows rh, rh+2, rh+4, rh+6
    float acc[4] = {0.f, 0.f, 0.f, 0.f};
    for (int k = 0; k < IN_DIM; ++k) {
        float w = sW[k * HID_DIM + c];
        acc[0] += sX[(rh + 0) * IN_DIM + k] * w;
        acc[1] += sX[(rh + 2) * IN_DIM + k] * w;
        acc[2] += sX[(rh + 4) * IN_DIM + k] * w;
        acc[3] += sX[(rh + 6) * IN_DIM + k] * w;
    }
    for (int j = 0; j < 4; ++j)
        h1[(row0 + rh + 2 * j) * HID_DIM + c] = acc[j];
}

// ---------------- agg1 init: b1 + self-loop term ----------------
__global__ void k_init_agg1(const float4* __restrict__ h1, const float* __restrict__ dinv,
                            const float4* __restrict__ b1, float4* __restrict__ agg1) {
    long i = (long)blockIdx.x * blockDim.x + threadIdx.x; // over N*32
    if (i < (long)N_NODES * (HID_DIM / 4)) {
        int node = (int)(i >> 5);
        int q    = (int)(i & 31);
        float s = dinv[node]; s = s * s;
        float4 v = h1[i], b = b1[q], o;
        o.x = b.x + s * v.x; o.y = b.y + s * v.y;
        o.z = b.z + s * v.z; o.w = b.w + s * v.w;
        agg1[i] = o;
    }
}

// ---------------- edge scatter layer 1 (128 floats / edge) ----------------
__global__ __launch_bounds__(256) void k_scatter1(const int* __restrict__ row,
                                                  const int* __restrict__ col,
                                                  const float* __restrict__ dinv,
                                                  const float4* __restrict__ h1,
                                                  float* __restrict__ agg1) {
    long t = (long)blockIdx.x * blockDim.x + threadIdx.x; // E * 32 float4-chunks
    if (t >= (long)N_EDGES * 32) return;
    int e = (int)(t >> 5), q = (int)(t & 31);
    int r = row[e], c = col[e];
    float nrm = dinv[r] * dinv[c];
    float4 v = h1[(long)r * 32 + q];
    float* dst = agg1 + (long)c * HID_DIM + q * 4;
    atomicAdd(dst + 0, nrm * v.x);
    atomicAdd(dst + 1, nrm * v.y);
    atomicAdd(dst + 2, nrm * v.z);
    atomicAdd(dst + 3, nrm * v.w);
}

// ---------------- GEMM2: h2 = relu(agg1) @ W2  (100000x128 @ 128x64) ------
__global__ __launch_bounds__(256) void k_gemm2(const float* __restrict__ agg1,
                                               const float* __restrict__ W2,
                                               float* __restrict__ h2) {
    __shared__ float sW[HID_DIM * EMB_DIM]; // 32 KB
    __shared__ float sH[8 * HID_DIM];       // 4 KB
    int t = threadIdx.x;
    long row0 = (long)blockIdx.x * 8;
    for (int i = t; i < HID_DIM * EMB_DIM; i += 256) sW[i] = W2[i];
    for (int i = t; i < 8 * HID_DIM; i += 256)
        sH[i] = fmaxf(agg1[row0 * HID_DIM + i], 0.0f); // fused ReLU
    __syncthreads();
    int c  = t & 63;
    int rh = t >> 6; // 0..3, owns rows rh and rh+4
    float acc[2] = {0.f, 0.f};
    for (int k = 0; k < HID_DIM; ++k) {
        float w = sW[k * EMB_DIM + c];
        acc[0] += sH[(rh + 0) * HID_DIM + k] * w;
        acc[1] += sH[(rh + 4) * HID_DIM + k] * w;
    }
    h2[(row0 + rh) * EMB_DIM + c]     = acc[0];
    h2[(row0 + rh + 4) * EMB_DIM + c] = acc[1];
}

// ---------------- out init: b2 + self-loop term ----------------
__global__ void k_init_out(const float4* __restrict__ h2, const float* __restrict__ dinv,
                           const float4* __restrict__ b2, float4* __restrict__ out) {
    long i = (long)blockIdx.x * blockDim.x + threadIdx.x; // over N*16
    if (i < (long)N_NODES * (EMB_DIM / 4)) {
        int node = (int)(i >> 4);
        int q    = (int)(i & 15);
        float s = dinv[node]; s = s * s;
        float4 v = h2[i], b = b2[q], o;
        o.x = b.x + s * v.x; o.y = b.y + s * v.y;
        o.z = b.z + s * v.z; o.w = b.w + s * v.w;
        out[i] = o;
    }
}

// ---------------- edge scatter layer 2 (64 floats / edge) ----------------
__global__ __launch_bounds__(256) void k_scatter2(const int* __restrict__ row,
                                                  const int* __restrict__ col,
                                                  const float* __restrict__ dinv,
                                                  const float4* __restrict__ h2,
                                                  float* __restrict__ out) {
    long t = (long)blockIdx.x * blockDim.x + threadIdx.x; // E * 16 float4-chunks
    if (t >= (long)N_EDGES * 16) return;
    int e = (int)(t >> 4), q = (int)(t & 15);
    int r = row[e], c = col[e];
    float nrm = dinv[r] * dinv[c];
    float4 v = h2[(long)r * 16 + q];
    float* dst = out + (long)c * EMB_DIM + q * 4;
    atomicAdd(dst + 0, nrm * v.x);
    atomicAdd(dst + 1, nrm * v.y);
    atomicAdd(dst + 2, nrm * v.z);
    atomicAdd(dst + 3, nrm * v.w);
}

extern "C" void kernel_launch(void* const* d_in, const int* in_sizes, int n_in,
                              void* d_out, int out_size, void* d_ws, size_t ws_size,
                              hipStream_t stream) {
    const float* x   = (const float*)d_in[0];
    const void*  eb  = d_in[1];
    const float* W1  = (const float*)d_in[2];
    const float* b1  = (const float*)d_in[3];
    const float* W2  = (const float*)d_in[4];
    const float* b2  = (const float*)d_in[5];
    float* out = (float*)d_out;

    // Workspace layout (bytes, all 16B-aligned):
    char* ws = (char*)d_ws;
    int*   deg     = (int*)  (ws + 0);          //  400,000 B
    float* dinv    = (float*)(ws + 400000);     //  400,000 B
    int*   flag    = (int*)  (ws + 800000);     //       16 B
    int*   edges32 = (int*)  (ws + 800128);     // 12,800,000 B
    float* h1      = (float*)(ws + 13600128);   // 51,200,000 B
    float* agg1    = (float*)(ws + 64800128);   // 51,200,000 B
    float* h2      = (float*)(ws + 116000128);  // 25,600,000 B  (total ~141.6 MB)

    int* row = edges32;            // edge_index[0]
    int* col = edges32 + N_EDGES;  // edge_index[1]

    hipMemsetAsync(deg, 0, N_NODES * sizeof(int), stream);
    k_detect_dtype<<<1, 64, 0, stream>>>((const unsigned int*)eb, flag);
    k_convert_edges<<<(2 * N_EDGES + 255) / 256, 256, 0, stream>>>(eb, flag, edges32);
    k_deg<<<(N_EDGES + 255) / 256, 256, 0, stream>>>(col, deg);
    k_dinv<<<(N_NODES + 255) / 256, 256, 0, stream>>>(deg, dinv);

    k_gemm1<<<N_NODES / 8, 256, 0, stream>>>(x, W1, h1);
    k_init_agg1<<<(N_NODES * (HID_DIM / 4) + 255) / 256, 256, 0, stream>>>(
        (const float4*)h1, dinv, (const float4*)b1, (float4*)agg1);
    k_scatter1<<<(int)(((long)N_EDGES * 32 + 255) / 256), 256, 0, stream>>>(
        row, col, dinv, (const float4*)h1, agg1);

    k_gemm2<<<N_NODES / 8, 256, 0, stream>>>(agg1, W2, h2);
    k_init_out<<<(N_NODES * (EMB_DIM / 4) + 255) / 256, 256, 0, stream>>>(
        (const float4*)h2, dinv, (const float4*)b2, (float4*)out);
    k_scatter2<<<(int)(((long)N_EDGES * 16 + 255) / 256), 256, 0, stream>>>(
        row, col, dinv, (const float4*)h2, out);
}

// Round 2
// 850.261 us; speedup vs baseline: 5.0529x; 5.0529x over previous
//
#include <hip/hip_runtime.h>

#define N_NODES 100000
#define N_EDGES 1600000
#define IN_DIM 64
#define HID_DIM 128
#define EMB_DIM 64

// ---------------- edge dtype handling ----------------
// Reference declares int64 edge_index, but JAX without x64 may give int32.
// Detect on device: for little-endian int64 with values in [0,1e5), every odd
// dword is 0. For int32 random values, impossible for 64 in a row.
__global__ void k_detect_dtype(const unsigned int* __restrict__ ebuf, int* __restrict__ flag) {
    if (blockIdx.x == 0 && threadIdx.x == 0) {
        int is64 = 1;
        for (int i = 0; i < 64; ++i)
            if (ebuf[2 * i + 1] != 0u) { is64 = 0; break; }
        *flag = is64;
    }
}

__global__ void k_convert_edges(const void* __restrict__ ebuf, const int* __restrict__ flag,
                                int* __restrict__ edges32) {
    int i = blockIdx.x * blockDim.x + threadIdx.x;
    if (i < 2 * N_EDGES) {
        int v;
        if (*flag) v = (int)((const long long*)ebuf)[i];
        else       v = ((const int*)ebuf)[i];
        edges32[i] = v;
    }
}

// ---------------- degree / normalization ----------------
__global__ void k_deg(const int* __restrict__ col, int* __restrict__ deg) {
    int e = blockIdx.x * blockDim.x + threadIdx.x;
    if (e < N_EDGES) atomicAdd(&deg[col[e]], 1);
}

__global__ void k_dinv(const int* __restrict__ deg, float* __restrict__ dinv) {
    int i = blockIdx.x * blockDim.x + threadIdx.x;
    if (i < N_NODES) dinv[i] = rsqrtf((float)(deg[i] + 1)); // +1 self loop
}

// ---------------- CSR build: exclusive scan of deg -> off, then fill -------
__global__ __launch_bounds__(1024) void k_scan1(const int* __restrict__ deg,
                                                int* __restrict__ off,
                                                int* __restrict__ bsum) {
    __shared__ int s[1024];
    int i = blockIdx.x * 1024 + threadIdx.x;
    int v = (i < N_NODES) ? deg[i] : 0;
    s[threadIdx.x] = v;
    __syncthreads();
    for (int d = 1; d < 1024; d <<= 1) {           // Hillis-Steele inclusive
        int t = (threadIdx.x >= d) ? s[threadIdx.x - d] : 0;
        __syncthreads();
        s[threadIdx.x] += t;
        __syncthreads();
    }
    if (i < N_NODES) off[i] = s[threadIdx.x] - v;  // exclusive
    if (threadIdx.x == 1023) bsum[blockIdx.x] = s[1023];
}

__global__ void k_scan2(int* __restrict__ bsum, int nb) {
    if (blockIdx.x == 0 && threadIdx.x == 0) {
        int run = 0;
        for (int b = 0; b < nb; ++b) { int v = bsum[b]; bsum[b] = run; run += v; }
    }
}

__global__ void k_scan3(int* __restrict__ off, const int* __restrict__ bsum,
                        int* __restrict__ cursor) {
    int i = blockIdx.x * blockDim.x + threadIdx.x;
    if (i < N_NODES) {
        int o = off[i] + bsum[i >> 10];
        off[i] = o;
        cursor[i] = o;
    }
    if (i == 0) off[N_NODES] = N_EDGES;
}

__global__ void k_fill(const int* __restrict__ row, const int* __restrict__ col,
                       int* __restrict__ cursor, int* __restrict__ csr_src) {
    int e = blockIdx.x * blockDim.x + threadIdx.x;
    if (e < N_EDGES) {
        int c = col[e];
        int p = atomicAdd(&cursor[c], 1);
        csr_src[p] = row[e];
    }
}

// ---------------- GEMM1: h1 = x @ W1  (100000x64 @ 64x128) ----------------
__global__ __launch_bounds__(256) void k_gemm1(const float* __restrict__ x,
                                               const float* __restrict__ W1,
                                               float* __restrict__ h1) {
    __shared__ float sW[IN_DIM * HID_DIM]; // 32 KB
    __shared__ float sX[8 * IN_DIM];       // 2 KB
    int t = threadIdx.x;
    long row0 = (long)blockIdx.x * 8;
    for (int i = t; i < IN_DIM * HID_DIM; i += 256) sW[i] = W1[i];
    for (int i = t; i < 8 * IN_DIM; i += 256) sX[i] = x[row0 * IN_DIM + i];
    __syncthreads();
    int c  = t & 127;
    int rh = t >> 7;
    float acc[4] = {0.f, 0.f, 0.f, 0.f};
    for (int k = 0; k < IN_DIM; ++k) {
        float w = sW[k * HID_DIM + c];
        acc[0] += sX[(rh + 0) * IN_DIM + k] * w;
        acc[1] += sX[(rh + 2) * IN_DIM + k] * w;
        acc[2] += sX[(rh + 4) * IN_DIM + k] * w;
        acc[3] += sX[(rh + 6) * IN_DIM + k] * w;
    }
    for (int j = 0; j < 4; ++j)
        h1[(row0 + rh + 2 * j) * HID_DIM + c] = acc[j];
}

// ------- agg1: per-node gather reduction over CSR (no atomics) -------------
// 2 nodes per 256-block; each node served by 2 waves (128 lanes = channels).
__global__ __launch_bounds__(256) void k_agg1(const int* __restrict__ off,
                                              const int* __restrict__ csr_src,
                                              const float* __restrict__ dinv,
                                              const float* __restrict__ h1,
                                              const float* __restrict__ b1,
                                              float* __restrict__ agg1) {
    int node = blockIdx.x * 2 + (threadIdx.x >> 7);
    int c    = threadIdx.x & 127;
    if (node >= N_NODES) return;
    float dc = dinv[node];
    float acc = b1[c] + dc * dc * h1[(long)node * HID_DIM + c]; // self loop + bias
    int e    = off[node];
    int eend = off[node + 1];
    for (; e < eend; ++e) {
        int r = csr_src[e];                 // wave-uniform -> broadcast
        acc += (dc * dinv[r]) * h1[(long)r * HID_DIM + c];
    }
    agg1[(long)node * HID_DIM + c] = acc;
}

// ---------------- GEMM2: h2 = relu(agg1) @ W2  (100000x128 @ 128x64) ------
__global__ __launch_bounds__(256) void k_gemm2(const float* __restrict__ agg1,
                                               const float* __restrict__ W2,
                                               float* __restrict__ h2) {
    __shared__ float sW[HID_DIM * EMB_DIM]; // 32 KB
    __shared__ float sH[8 * HID_DIM];       // 4 KB
    int t = threadIdx.x;
    long row0 = (long)blockIdx.x * 8;
    for (int i = t; i < HID_DIM * EMB_DIM; i += 256) sW[i] = W2[i];
    for (int i = t; i < 8 * HID_DIM; i += 256)
        sH[i] = fmaxf(agg1[row0 * HID_DIM + i], 0.0f); // fused ReLU
    __syncthreads();
    int c  = t & 63;
    int rh = t >> 6;
    float acc[2] = {0.f, 0.f};
    for (int k = 0; k < HID_DIM; ++k) {
        float w = sW[k * EMB_DIM + c];
        acc[0] += sH[(rh + 0) * HID_DIM + k] * w;
        acc[1] += sH[(rh + 4) * HID_DIM + k] * w;
    }
    h2[(row0 + rh) * EMB_DIM + c]     = acc[0];
    h2[(row0 + rh + 4) * EMB_DIM + c] = acc[1];
}

// ------- agg2: per-node gather reduction, 64 channels ----------------------
// 4 nodes per 256-block; each node served by 1 wave (64 lanes = channels).
__global__ __launch_bounds__(256) void k_agg2(const int* __restrict__ off,
                                              const int* __restrict__ csr_src,
                                              const float* __restrict__ dinv,
                                              const float* __restrict__ h2,
                                              const float* __restrict__ b2,
                                              float* __restrict__ out) {
    int node = blockIdx.x * 4 + (threadIdx.x >> 6);
    int c    = threadIdx.x & 63;
    if (node >= N_NODES) return;
    float dc = dinv[node];
    float acc = b2[c] + dc * dc * h2[(long)node * EMB_DIM + c];
    int e    = off[node];
    int eend = off[node + 1];
    for (; e < eend; ++e) {
        int r = csr_src[e];
        acc += (dc * dinv[r]) * h2[(long)r * EMB_DIM + c];
    }
    out[(long)node * EMB_DIM + c] = acc;
}

extern "C" void kernel_launch(void* const* d_in, const int* in_sizes, int n_in,
                              void* d_out, int out_size, void* d_ws, size_t ws_size,
                              hipStream_t stream) {
    const float* x   = (const float*)d_in[0];
    const void*  eb  = d_in[1];
    const float* W1  = (const float*)d_in[2];
    const float* b1  = (const float*)d_in[3];
    const float* W2  = (const float*)d_in[4];
    const float* b2  = (const float*)d_in[5];
    float* out = (float*)d_out;

    // Workspace layout (bytes, 64B-aligned blocks):
    char* ws = (char*)d_ws;
    int*   deg     = (int*)  (ws + 0);           //    400,000
    float* dinv    = (float*)(ws + 400000);      //    400,000
    int*   flag    = (int*)  (ws + 800000);      //         16
    int*   bsum    = (int*)  (ws + 800064);      //        512
    int*   off     = (int*)  (ws + 800576);      //    400,004
    int*   cursor  = (int*)  (ws + 1200640);     //    400,004
    int*   edges32 = (int*)  (ws + 1600768);     // 12,800,000
    int*   csr_src = (int*)  (ws + 14400768);    //  6,400,000
    float* h1      = (float*)(ws + 20800768);    // 51,200,000
    float* agg1    = (float*)(ws + 72000768);    // 51,200,000
    float* h2      = (float*)(ws + 20800768);    // alias h1 (dead after agg1)
    // total: 123,200,768 B

    int* row = edges32;
    int* col = edges32 + N_EDGES;

    hipMemsetAsync(deg, 0, N_NODES * sizeof(int), stream);
    k_detect_dtype<<<1, 64, 0, stream>>>((const unsigned int*)eb, flag);
    k_convert_edges<<<(2 * N_EDGES + 255) / 256, 256, 0, stream>>>(eb, flag, edges32);
    k_deg<<<(N_EDGES + 255) / 256, 256, 0, stream>>>(col, deg);
    k_dinv<<<(N_NODES + 255) / 256, 256, 0, stream>>>(deg, dinv);

    const int nb = (N_NODES + 1023) / 1024; // 98
    k_scan1<<<nb, 1024, 0, stream>>>(deg, off, bsum);
    k_scan2<<<1, 64, 0, stream>>>(bsum, nb);
    k_scan3<<<(N_NODES + 255) / 256, 256, 0, stream>>>(off, bsum, cursor);
    k_fill<<<(N_EDGES + 255) / 256, 256, 0, stream>>>(row, col, cursor, csr_src);

    k_gemm1<<<N_NODES / 8, 256, 0, stream>>>(x, W1, h1);
    k_agg1<<<(N_NODES + 1) / 2, 256, 0, stream>>>(off, csr_src, dinv, h1, b1, agg1);

    k_gemm2<<<N_NODES / 8, 256, 0, stream>>>(agg1, W2, h2);
    k_agg2<<<(N_NODES + 3) / 4, 256, 0, stream>>>(off, csr_src, dinv, h2, b2, out);
}

// Round 3
// 561.649 us; speedup vs baseline: 7.6495x; 1.5139x over previous
//
#include <hip/hip_runtime.h>

#define N_NODES 100000
#define N_EDGES 1600000
#define IN_DIM 64
#define HID_DIM 128
#define EMB_DIM 64

// ---------------- edge dtype handling ----------------
// Reference declares int64 edge_index, but JAX without x64 may give int32.
// Detect on device: little-endian int64 values in [0,1e5) -> every odd dword 0.
__global__ void k_detect_dtype(const unsigned int* __restrict__ ebuf, int* __restrict__ flag) {
    if (blockIdx.x == 0 && threadIdx.x == 0) {
        int is64 = 1;
        for (int i = 0; i < 64; ++i)
            if (ebuf[2 * i + 1] != 0u) { is64 = 0; break; }
        *flag = is64;
    }
}

__global__ void k_convert_edges(const void* __restrict__ ebuf, const int* __restrict__ flag,
                                int* __restrict__ edges32) {
    int i = blockIdx.x * blockDim.x + threadIdx.x;
    if (i < 2 * N_EDGES) {
        int v;
        if (*flag) v = (int)((const long long*)ebuf)[i];
        else       v = ((const int*)ebuf)[i];
        edges32[i] = v;
    }
}

// ---------------- degree / normalization ----------------
__global__ void k_deg(const int* __restrict__ col, int* __restrict__ deg) {
    int e = blockIdx.x * blockDim.x + threadIdx.x;
    if (e < N_EDGES) atomicAdd(&deg[col[e]], 1);
}

__global__ void k_dinv(const int* __restrict__ deg, float* __restrict__ dinv) {
    int i = blockIdx.x * blockDim.x + threadIdx.x;
    if (i < N_NODES) dinv[i] = rsqrtf((float)(deg[i] + 1)); // +1 self loop
}

// ---------------- CSR build: exclusive scan of deg -> off, then fill -------
__global__ __launch_bounds__(1024) void k_scan1(const int* __restrict__ deg,
                                                int* __restrict__ off,
                                                int* __restrict__ bsum) {
    __shared__ int s[1024];
    int i = blockIdx.x * 1024 + threadIdx.x;
    int v = (i < N_NODES) ? deg[i] : 0;
    s[threadIdx.x] = v;
    __syncthreads();
    for (int d = 1; d < 1024; d <<= 1) {           // Hillis-Steele inclusive
        int t = (threadIdx.x >= d) ? s[threadIdx.x - d] : 0;
        __syncthreads();
        s[threadIdx.x] += t;
        __syncthreads();
    }
    if (i < N_NODES) off[i] = s[threadIdx.x] - v;  // exclusive
    if (threadIdx.x == 1023) bsum[blockIdx.x] = s[1023];
}

__global__ void k_scan2(int* __restrict__ bsum, int nb) {
    if (blockIdx.x == 0 && threadIdx.x == 0) {
        int run = 0;
        for (int b = 0; b < nb; ++b) { int v = bsum[b]; bsum[b] = run; run += v; }
    }
}

__global__ void k_scan3(int* __restrict__ off, const int* __restrict__ bsum,
                        int* __restrict__ cursor) {
    int i = blockIdx.x * blockDim.x + threadIdx.x;
    if (i < N_NODES) {
        int o = off[i] + bsum[i >> 10];
        off[i] = o;
        cursor[i] = o;
    }
    if (i == 0) off[N_NODES] = N_EDGES;
}

// fill csr_src + per-edge norm (dinv[src]*dinv[dst]) so the hot agg loop
// streams norms sequentially instead of chasing dinv[] randomly.
__global__ void k_fill(const int* __restrict__ row, const int* __restrict__ col,
                       const float* __restrict__ dinv,
                       int* __restrict__ cursor, int* __restrict__ csr_src,
                       float* __restrict__ csr_norm) {
    int e = blockIdx.x * blockDim.x + threadIdx.x;
    if (e < N_EDGES) {
        int r = row[e], c = col[e];
        int p = atomicAdd(&cursor[c], 1);
        csr_src[p]  = r;
        csr_norm[p] = dinv[r] * dinv[c];
    }
}

// ---------------- GEMM1: h1 = x @ W1  (100000x64 @ 64x128) ----------------
// 16 rows/block; thread = (row-pair, quad-col). 3 LDS reads per 8 FMAs.
__global__ __launch_bounds__(256) void k_gemm1(const float4* __restrict__ x4,
                                               const float4* __restrict__ W14,
                                               float4* __restrict__ h14) {
    __shared__ float sW[IN_DIM * HID_DIM]; // 32 KB
    __shared__ float sX[16 * IN_DIM];      // 4 KB
    float4* sW4 = (float4*)sW;
    float4* sX4 = (float4*)sX;
    int t = threadIdx.x;
    long row0 = (long)blockIdx.x * 16;
    for (int i = t; i < IN_DIM * HID_DIM / 4; i += 256) sW4[i] = W14[i];
    sX4[t] = x4[row0 * (IN_DIM / 4) + t];  // 256 float4 = 16 rows
    __syncthreads();
    int qc = t & 31;        // quad-col: cols [4qc..4qc+3]
    int r  = (t >> 5) * 2;  // rows r, r+1
    float4 a0 = {0,0,0,0}, a1 = {0,0,0,0};
    for (int k = 0; k < IN_DIM; ++k) {
        float4 w = sW4[k * 32 + qc];
        float x0 = sX[r * IN_DIM + k];
        float x1 = sX[(r + 1) * IN_DIM + k];
        a0.x += x0 * w.x; a0.y += x0 * w.y; a0.z += x0 * w.z; a0.w += x0 * w.w;
        a1.x += x1 * w.x; a1.y += x1 * w.y; a1.z += x1 * w.z; a1.w += x1 * w.w;
    }
    h14[(row0 + r) * 32 + qc]     = a0;
    h14[(row0 + r + 1) * 32 + qc] = a1;
}

// ------- agg1: 1 wave per node, lane = channel-pair (float2), x4 unroll ----
__global__ __launch_bounds__(256) void k_agg1(const int* __restrict__ off,
                                              const int* __restrict__ csr_src,
                                              const float* __restrict__ csr_norm,
                                              const float* __restrict__ dinv,
                                              const float2* __restrict__ h1v,
                                              const float2* __restrict__ b1v,
                                              float2* __restrict__ agg1v) {
    int node = blockIdx.x * 4 + (threadIdx.x >> 6);
    int lane = threadIdx.x & 63;
    if (node >= N_NODES) return;
    float dc = dinv[node];
    float2 b = b1v[lane];
    float2 h = h1v[(long)node * 64 + lane];
    float2 acc;
    acc.x = b.x + dc * dc * h.x;
    acc.y = b.y + dc * dc * h.y;
    int e    = off[node];
    int eend = off[node + 1];
    for (; e + 4 <= eend; e += 4) {
        int   s0 = csr_src[e],     s1 = csr_src[e + 1];
        int   s2 = csr_src[e + 2], s3 = csr_src[e + 3];
        float n0 = csr_norm[e],     n1 = csr_norm[e + 1];
        float n2 = csr_norm[e + 2], n3 = csr_norm[e + 3];
        float2 v0 = h1v[(long)s0 * 64 + lane];
        float2 v1 = h1v[(long)s1 * 64 + lane];
        float2 v2 = h1v[(long)s2 * 64 + lane];
        float2 v3 = h1v[(long)s3 * 64 + lane];
        acc.x += n0 * v0.x; acc.y += n0 * v0.y;
        acc.x += n1 * v1.x; acc.y += n1 * v1.y;
        acc.x += n2 * v2.x; acc.y += n2 * v2.y;
        acc.x += n3 * v3.x; acc.y += n3 * v3.y;
    }
    for (; e < eend; ++e) {
        int s = csr_src[e]; float n = csr_norm[e];
        float2 v = h1v[(long)s * 64 + lane];
        acc.x += n * v.x; acc.y += n * v.y;
    }
    agg1v[(long)node * 64 + lane] = acc;
}

// ---------------- GEMM2: h2 = relu(agg1) @ W2  (100000x128 @ 128x64) ------
// 32 rows/block; ReLU fused into LDS staging.
__global__ __launch_bounds__(256) void k_gemm2(const float4* __restrict__ agg14,
                                               const float4* __restrict__ W24,
                                               float4* __restrict__ h24) {
    __shared__ float sW[HID_DIM * EMB_DIM]; // 32 KB
    __shared__ float sH[32 * HID_DIM];      // 16 KB
    float4* sW4 = (float4*)sW;
    float4* sH4 = (float4*)sH;
    int t = threadIdx.x;
    long row0 = (long)blockIdx.x * 32;
    for (int i = t; i < HID_DIM * EMB_DIM / 4; i += 256) sW4[i] = W24[i];
    for (int i = t; i < 32 * HID_DIM / 4; i += 256) {
        float4 v = agg14[row0 * (HID_DIM / 4) + i];
        v.x = fmaxf(v.x, 0.f); v.y = fmaxf(v.y, 0.f);
        v.z = fmaxf(v.z, 0.f); v.w = fmaxf(v.w, 0.f);
        sH4[i] = v;
    }
    __syncthreads();
    int qc = t & 15;        // quad-col: cols [4qc..4qc+3]
    int r  = (t >> 4) * 2;  // rows r, r+1
    float4 a0 = {0,0,0,0}, a1 = {0,0,0,0};
    for (int k = 0; k < HID_DIM; ++k) {
        float4 w = sW4[k * 16 + qc];
        float x0 = sH[r * HID_DIM + k];
        float x1 = sH[(r + 1) * HID_DIM + k];
        a0.x += x0 * w.x; a0.y += x0 * w.y; a0.z += x0 * w.z; a0.w += x0 * w.w;
        a1.x += x1 * w.x; a1.y += x1 * w.y; a1.z += x1 * w.z; a1.w += x1 * w.w;
    }
    h24[(row0 + r) * 16 + qc]     = a0;
    h24[(row0 + r + 1) * 16 + qc] = a1;
}

// ------- agg2: 1 wave per node, lane = channel, x4 unroll ------------------
__global__ __launch_bounds__(256) void k_agg2(const int* __restrict__ off,
                                              const int* __restrict__ csr_src,
                                              const float* __restrict__ csr_norm,
                                              const float* __restrict__ dinv,
                                              const float* __restrict__ h2,
                                              const float* __restrict__ b2,
                                              float* __restrict__ out) {
    int node = blockIdx.x * 4 + (threadIdx.x >> 6);
    int c    = threadIdx.x & 63;
    if (node >= N_NODES) return;
    float dc = dinv[node];
    float acc = b2[c] + dc * dc * h2[(long)node * EMB_DIM + c];
    int e    = off[node];
    int eend = off[node + 1];
    for (; e + 4 <= eend; e += 4) {
        int   s0 = csr_src[e],     s1 = csr_src[e + 1];
        int   s2 = csr_src[e + 2], s3 = csr_src[e + 3];
        float n0 = csr_norm[e],     n1 = csr_norm[e + 1];
        float n2 = csr_norm[e + 2], n3 = csr_norm[e + 3];
        float v0 = h2[(long)s0 * EMB_DIM + c];
        float v1 = h2[(long)s1 * EMB_DIM + c];
        float v2 = h2[(long)s2 * EMB_DIM + c];
        float v3 = h2[(long)s3 * EMB_DIM + c];
        acc += n0 * v0 + n1 * v1 + n2 * v2 + n3 * v3;
    }
    for (; e < eend; ++e) {
        acc += csr_norm[e] * h2[(long)csr_src[e] * EMB_DIM + c];
    }
    out[(long)node * EMB_DIM + c] = acc;
}

extern "C" void kernel_launch(void* const* d_in, const int* in_sizes, int n_in,
                              void* d_out, int out_size, void* d_ws, size_t ws_size,
                              hipStream_t stream) {
    const float* x   = (const float*)d_in[0];
    const void*  eb  = d_in[1];
    const float* W1  = (const float*)d_in[2];
    const float* b1  = (const float*)d_in[3];
    const float* W2  = (const float*)d_in[4];
    const float* b2  = (const float*)d_in[5];
    float* out = (float*)d_out;

    // Workspace layout (bytes):
    char* ws = (char*)d_ws;
    int*   deg      = (int*)  (ws + 0);           //    400,000
    float* dinv     = (float*)(ws + 400000);      //    400,000
    int*   flag     = (int*)  (ws + 800000);      //         16
    int*   bsum     = (int*)  (ws + 800064);      //        512
    int*   off      = (int*)  (ws + 800576);      //    400,004
    int*   cursor   = (int*)  (ws + 1200640);     //    400,004, pad
    int*   edges32  = (int*)  (ws + 1600768);     // 12,800,000
    int*   csr_src  = (int*)  (ws + 14400768);    //  6,400,000
    float* csr_norm = (float*)(ws + 20800768);    //  6,400,000
    float* h1       = (float*)(ws + 27200768);    // 51,200,000
    float* agg1     = (float*)(ws + 78400768);    // 51,200,000
    float* h2       = (float*)(ws + 27200768);    // alias h1 (dead after agg1)
    // total: 129,600,768 B

    int* row = edges32;
    int* col = edges32 + N_EDGES;

    hipMemsetAsync(deg, 0, N_NODES * sizeof(int), stream);
    k_detect_dtype<<<1, 64, 0, stream>>>((const unsigned int*)eb, flag);
    k_convert_edges<<<(2 * N_EDGES + 255) / 256, 256, 0, stream>>>(eb, flag, edges32);
    k_deg<<<(N_EDGES + 255) / 256, 256, 0, stream>>>(col, deg);
    k_dinv<<<(N_NODES + 255) / 256, 256, 0, stream>>>(deg, dinv);

    const int nb = (N_NODES + 1023) / 1024; // 98
    k_scan1<<<nb, 1024, 0, stream>>>(deg, off, bsum);
    k_scan2<<<1, 64, 0, stream>>>(bsum, nb);
    k_scan3<<<(N_NODES + 255) / 256, 256, 0, stream>>>(off, bsum, cursor);
    k_fill<<<(N_EDGES + 255) / 256, 256, 0, stream>>>(row, col, dinv, cursor, csr_src, csr_norm);

    k_gemm1<<<N_NODES / 16, 256, 0, stream>>>((const float4*)x, (const float4*)W1, (float4*)h1);
    k_agg1<<<(N_NODES + 3) / 4, 256, 0, stream>>>(off, csr_src, csr_norm, dinv,
                                                  (const float2*)h1, (const float2*)b1,
                                                  (float2*)agg1);

    k_gemm2<<<N_NODES / 32, 256, 0, stream>>>((const float4*)agg1, (const float4*)W2, (float4*)h2);
    k_agg2<<<(N_NODES + 3) / 4, 256, 0, stream>>>(off, csr_src, csr_norm, dinv, h2, b2, out);
}